// Round 8
// baseline (886.787 us; speedup 1.0000x reference)
//
#include <hip/hip_runtime.h>

// GNN: 2-layer bipartite GraphConv + link decoder.
// Round 8: fused aggregation+conv (mean tile staged in LDS, one barrier,
// conv reads A from LDS -> no meanb round-trip, no separate conv dispatch).
// W1 folded into layer-1 weights (R7), counting-sort CSR (R6).

#define D 128
#define PGB 256   // partition grid blocks

typedef float f32x4 __attribute__((ext_vector_type(4)));
typedef short s16x8 __attribute__((ext_vector_type(8)));

__device__ __forceinline__ float lo16(unsigned u) { return __uint_as_float(u << 16); }
__device__ __forceinline__ float hi16(unsigned u) { return __uint_as_float(u & 0xffff0000u); }
__device__ __forceinline__ unsigned short pkb(float f) {
  unsigned b = __float_as_uint(f);
  return (unsigned short)((b + 0x7fffu + ((b >> 16) & 1u)) >> 16);
}
__device__ __forceinline__ unsigned pk2(float a, float b) {
  return (unsigned)pkb(a) | ((unsigned)pkb(b) << 16);
}

union U4S8 { uint4 u; s16x8 s; };

// ---------------- CSR build: counting-sort partition (no global atomics) ----

__global__ __launch_bounds__(256) void part_hist_k(
    const int* __restrict__ dst, int* __restrict__ histmat,
    int E, int nbins, int shift) {
  __shared__ int hist[256];
  const int t = threadIdx.x, blk = blockIdx.x;
  hist[t] = 0;
  __syncthreads();
  const int chunk = (E + PGB - 1) / PGB;
  const int e0 = blk * chunk, e1 = min(E, e0 + chunk);
  for (int i = e0 + t; i < e1; i += 256)
    atomicAdd(&hist[dst[i] >> shift], 1);
  __syncthreads();
  if (t < nbins) histmat[(size_t)t * PGB + blk] = hist[t];
}

__global__ void scan_chunk_k(const int* __restrict__ in, int* __restrict__ out,
                             int* __restrict__ sums, int n) {
  __shared__ int lds[256];
  int t = threadIdx.x;
  int base = blockIdx.x * 1024 + t * 4;
  int v0 = (base + 0 < n) ? in[base + 0] : 0;
  int v1 = (base + 1 < n) ? in[base + 1] : 0;
  int v2 = (base + 2 < n) ? in[base + 2] : 0;
  int v3 = (base + 3 < n) ? in[base + 3] : 0;
  int s = v0 + v1 + v2 + v3;
  lds[t] = s;
  __syncthreads();
  for (int off = 1; off < 256; off <<= 1) {
    int x = (t >= off) ? lds[t - off] : 0;
    __syncthreads();
    lds[t] += x;
    __syncthreads();
  }
  int excl = lds[t] - s;
  if (t == 255) sums[blockIdx.x] = lds[255];
  if (base + 0 < n) out[base + 0] = excl; excl += v0;
  if (base + 1 < n) out[base + 1] = excl; excl += v1;
  if (base + 2 < n) out[base + 2] = excl; excl += v2;
  if (base + 3 < n) out[base + 3] = excl;
}

__global__ void scan_tops_k(int* __restrict__ sums, int nb) {
  if (threadIdx.x == 0 && blockIdx.x == 0) {
    int run = 0;
    for (int i = 0; i < nb; ++i) { int x = sums[i]; sums[i] = run; run += x; }
  }
}

__global__ void scan_add_k(int* __restrict__ out, const int* __restrict__ sums, int n) {
  int i = blockIdx.x * 256 + threadIdx.x;
  if (i < n) out[i] += sums[i >> 10];
}

__global__ __launch_bounds__(256) void part_scatter_k(
    const int* __restrict__ src, const int* __restrict__ dst,
    const int* __restrict__ histoff, unsigned* __restrict__ binned,
    int E, int nbins, int shift) {
  __shared__ int cur[256];
  const int t = threadIdx.x, blk = blockIdx.x;
  if (t < nbins) cur[t] = histoff[(size_t)t * PGB + blk];
  __syncthreads();
  const int chunk = (E + PGB - 1) / PGB;
  const int e0 = blk * chunk, e1 = min(E, e0 + chunk);
  const int mask = (1 << shift) - 1;
  for (int i = e0 + t; i < e1; i += 256) {
    int d = dst[i], s = src[i];
    int b = d >> shift;
    int p = atomicAdd(&cur[b], 1);   // LDS atomic
    binned[p] = ((unsigned)(d & mask) << 17) | (unsigned)s;
  }
}

__global__ __launch_bounds__(256) void csr_bin_k(
    const unsigned* __restrict__ binned, const int* __restrict__ histoff,
    int* __restrict__ csr, int* __restrict__ off, int* __restrict__ cnt,
    float* __restrict__ inv, int E, int nbins, int shift, int N) {
  __shared__ int lcnt[512], lex[512], tmp[256];
  const int t = threadIdx.x, bin = blockIdx.x;
  const int bw = 1 << shift;
  const int e0 = histoff[(size_t)bin * PGB];
  const int e1 = (bin + 1 < nbins) ? histoff[(size_t)(bin + 1) * PGB] : E;
  lcnt[t] = 0; lcnt[t + 256] = 0;
  __syncthreads();
  for (int i = e0 + t; i < e1; i += 256)
    atomicAdd(&lcnt[binned[i] >> 17], 1);   // LDS atomic
  __syncthreads();
  int a = lcnt[t], b = lcnt[t + 256];
  tmp[t] = a; __syncthreads();
  for (int o = 1; o < 256; o <<= 1) {
    int x = (t >= o) ? tmp[t - o] : 0;
    __syncthreads(); tmp[t] += x; __syncthreads();
  }
  int inclA = tmp[t], totA = tmp[255];
  __syncthreads();
  tmp[t] = b; __syncthreads();
  for (int o = 1; o < 256; o <<= 1) {
    int x = (t >= o) ? tmp[t - o] : 0;
    __syncthreads(); tmp[t] += x; __syncthreads();
  }
  int inclB = tmp[t];
  lex[t] = inclA - a;
  lex[t + 256] = totA + inclB - b;
  __syncthreads();
  const int based = bin << shift;
  const int nd = min(bw, N - based);
  for (int dl = t; dl < nd; dl += 256) {
    int c = lcnt[dl];
    off[based + dl] = e0 + lex[dl];
    cnt[based + dl] = c;
    inv[based + dl] = 1.0f / fmaxf((float)c, 1.0f);
  }
  __syncthreads();
  lcnt[t] = lex[t]; lcnt[t + 256] = lex[t + 256];
  __syncthreads();
  for (int i = e0 + t; i < e1; i += 256) {
    unsigned u = binned[i];
    int dl = (int)(u >> 17);
    int p = atomicAdd(&lcnt[dl], 1);   // LDS atomic
    csr[e0 + p] = (int)(u & 0x1FFFFu);
  }
}

// ---------------- conversions / weight prep ----------------

__global__ void cvt_bf16_k(const float* __restrict__ in, unsigned short* __restrict__ out, int n4) {
  int i = blockIdx.x * 256 + threadIdx.x;
  if (i < n4) {
    float4 v = ((const float4*)in)[i];
    ushort4 o;
    o.x = pkb(v.x); o.y = pkb(v.y); o.z = pkb(v.z); o.w = pkb(v.w);
    ((ushort4*)out)[i] = o;
  }
}

__global__ void pack_wcat_k(const float* __restrict__ Wrel, const float* __restrict__ Wroot,
                            unsigned short* __restrict__ Wcat) {
  int idx = blockIdx.x * 256 + threadIdx.x;  // 32768
  int n = idx >> 8, k = idx & 255;
  float v = (k < 128) ? Wrel[(n << 7) + k] : Wroot[(n << 7) + k - 128];
  Wcat[idx] = pkb(v);
}

// WcatF[i][kk] = sum_o W1[i][o] * (kk<128 ? Wrel[o][kk] : Wroot[o][kk-128]);
// biasF[i] = sum_o W1[i][o]*brel[o] (+ b1[i] if b1 != null)
__global__ __launch_bounds__(256) void fuse_w_k(
    const float* __restrict__ W1, const float* __restrict__ Wrel,
    const float* __restrict__ Wroot, const float* __restrict__ brel,
    const float* __restrict__ b1, unsigned short* __restrict__ Wf,
    float* __restrict__ biasF) {
  const int i = blockIdx.x;      // output channel 0..127
  const int kk = threadIdx.x;    // 0..255
  const float* __restrict__ Wsrc = (kk < 128) ? Wrel : Wroot;
  const int k = kk & 127;
  float s = 0.f;
  for (int o = 0; o < 128; ++o)
    s += W1[i * 128 + o] * Wsrc[o * 128 + k];
  Wf[i * 256 + kk] = pkb(s);
  if (kk == 0) {
    float sb = b1 ? b1[i] : 0.f;
    for (int o = 0; o < 128; ++o) sb += W1[i * 128 + o] * brel[o];
    biasF[i] = sb;
  }
}

// ---------------- fused aggregation + conv ----------------
// Block = 128 dst rows. Phase 1: wave w mean-aggregates rows [w*32, w*32+32)
// into LDS tile Am[128][136] (bf16, padded: A-frag ds_read lands 2-way = free).
// Phase 2: out[row][128] = [mean | xroot] @ Wcat^T + bias, A1 from LDS.

__global__ __launch_bounds__(256) void agg_conv_k(
    const unsigned short* __restrict__ xsrc,
    const unsigned short* __restrict__ xroot,
    const int* __restrict__ csr, const int* __restrict__ off,
    const int* __restrict__ cnt, const float* __restrict__ inv,
    const unsigned short* __restrict__ Wcat, const float* __restrict__ bias,
    unsigned short* __restrict__ out, int n, int relu) {
  __shared__ unsigned short Am[128][136];
  const int t = threadIdx.x;
  const int l = t & 63, wv = t >> 6;
  const int q = l >> 4, sl = l & 15;
  const int row0 = blockIdx.x * 128;

  // ---- phase 1: aggregate 32 rows per wave ----
  for (int rr = 0; rr < 32; ++rr) {
    const int lr = wv * 32 + rr;
    const int row = row0 + lr;
    int o = 0, deg = 0;
    if (row < n) { o = off[row]; deg = cnt[row]; }
    float acc[8] = {0.f, 0.f, 0.f, 0.f, 0.f, 0.f, 0.f, 0.f};
    int sN[4];
#pragma unroll
    for (int j = 0; j < 4; ++j) {
      int e = j * 4 + q;
      sN[j] = (e < deg) ? csr[o + e] : -1;
    }
    for (int i = 0; i < deg; i += 16) {
      int cu[4];
#pragma unroll
      for (int j = 0; j < 4; ++j) {
        cu[j] = sN[j];
        int e = i + 16 + j * 4 + q;
        sN[j] = (e < deg) ? csr[o + e] : -1;
      }
      uint4 v[4];
#pragma unroll
      for (int j = 0; j < 4; ++j)
        if (cu[j] >= 0) v[j] = *(const uint4*)(xsrc + (size_t)cu[j] * 128 + sl * 8);
#pragma unroll
      for (int j = 0; j < 4; ++j) {
        if (cu[j] >= 0) {
          acc[0] += lo16(v[j].x); acc[1] += hi16(v[j].x);
          acc[2] += lo16(v[j].y); acc[3] += hi16(v[j].y);
          acc[4] += lo16(v[j].z); acc[5] += hi16(v[j].z);
          acc[6] += lo16(v[j].w); acc[7] += hi16(v[j].w);
        }
      }
    }
#pragma unroll
    for (int j = 0; j < 8; ++j) {
      acc[j] += __shfl_xor(acc[j], 16);
      acc[j] += __shfl_xor(acc[j], 32);
    }
    if (q == 0) {
      float iv = (row < n) ? inv[row] : 1.0f;
      uint4 r;
      r.x = pk2(acc[0] * iv, acc[1] * iv);
      r.y = pk2(acc[2] * iv, acc[3] * iv);
      r.z = pk2(acc[4] * iv, acc[5] * iv);
      r.w = pk2(acc[6] * iv, acc[7] * iv);
      *(uint4*)&Am[lr][sl * 8] = r;
    }
  }
  __syncthreads();

  // ---- phase 2: conv, A1 from LDS, A2 (root) + B from global/L2 ----
  const int g = l >> 4;
  f32x4 acc2[2][8] = {};
  int rowa[2];
#pragma unroll
  for (int fr = 0; fr < 2; ++fr) {
    int r = row0 + wv * 32 + fr * 16 + (l & 15);
    rowa[fr] = r < n ? r : n - 1;
  }

  for (int ch = 0; ch < 8; ++ch) {
    const int kb = (ch & 3) * 32;
    s16x8 av[2];
    if (ch < 4) {
#pragma unroll
      for (int fr = 0; fr < 2; ++fr)
        av[fr] = *(const s16x8*)&Am[wv * 32 + fr * 16 + (l & 15)][kb + g * 8];
    } else {
#pragma unroll
      for (int fr = 0; fr < 2; ++fr)
        av[fr] = *(const s16x8*)(xroot + (size_t)rowa[fr] * 128 + kb + g * 8);
    }
#pragma unroll
    for (int fc = 0; fc < 8; ++fc) {
      int col = fc * 16 + (l & 15);
      s16x8 bv = *(const s16x8*)(Wcat + (size_t)col * 256 + ch * 32 + g * 8);
#pragma unroll
      for (int fr = 0; fr < 2; ++fr)
        acc2[fr][fc] = __builtin_amdgcn_mfma_f32_16x16x32_bf16(av[fr], bv, acc2[fr][fc], 0, 0, 0);
    }
  }

#pragma unroll
  for (int fc = 0; fc < 8; ++fc) {
    int col = fc * 16 + (l & 15);
    float bb = bias[col];
#pragma unroll
    for (int fr = 0; fr < 2; ++fr) {
      int rbase = row0 + wv * 32 + fr * 16 + g * 4;
#pragma unroll
      for (int reg = 0; reg < 4; ++reg) {
        int row = rbase + reg;
        if (row < n) {
          float v = acc2[fr][fc][reg] + bb;
          if (relu) v = fmaxf(v, 0.f);
          out[(size_t)row * 128 + col] = pkb(v);
        }
      }
    }
  }
}

// ---------------- decoder: h1 = relu(Pv[lv]-Ph[lh]); stage2 MFMA; dot ----------

__global__ __launch_bounds__(256) void dec2_k(
    const unsigned short* __restrict__ Pv, const unsigned short* __restrict__ Ph,
    const int* __restrict__ lv, const int* __restrict__ lh,
    const unsigned short* __restrict__ W2b, const float* __restrict__ b2,
    const float* __restrict__ Wp, const float* __restrict__ bp,
    float* __restrict__ out, int L) {
  const int t = threadIdx.x;
  const int l = t & 63, wv = t >> 6;
  const int g = l >> 4;
  const int row0 = blockIdx.x * 64 + wv * 16;

  int rowc = row0 + (l & 15);
  rowc = rowc < L ? rowc : L - 1;
  const int iv = lv[rowc], ih = lh[rowc];
  const unsigned short* __restrict__ pv = Pv + (size_t)iv * 128 + g * 8;
  const unsigned short* __restrict__ ph = Ph + (size_t)ih * 128 + g * 8;

  uint4 A[4], B[4];
#pragma unroll
  for (int ch = 0; ch < 4; ++ch) A[ch] = *(const uint4*)(pv + ch * 32);
#pragma unroll
  for (int ch = 0; ch < 4; ++ch) B[ch] = *(const uint4*)(ph + ch * 32);

  s16x8 e[4];
#pragma unroll
  for (int ch = 0; ch < 4; ++ch) {
    U4S8 u;
    u.u.x = pk2(fmaxf(lo16(A[ch].x) - lo16(B[ch].x), 0.f), fmaxf(hi16(A[ch].x) - hi16(B[ch].x), 0.f));
    u.u.y = pk2(fmaxf(lo16(A[ch].y) - lo16(B[ch].y), 0.f), fmaxf(hi16(A[ch].y) - hi16(B[ch].y), 0.f));
    u.u.z = pk2(fmaxf(lo16(A[ch].z) - lo16(B[ch].z), 0.f), fmaxf(hi16(A[ch].z) - hi16(B[ch].z), 0.f));
    u.u.w = pk2(fmaxf(lo16(A[ch].w) - lo16(B[ch].w), 0.f), fmaxf(hi16(A[ch].w) - hi16(B[ch].w), 0.f));
    e[ch] = u.s;
  }

  f32x4 acc2[2] = {};
#pragma unroll
  for (int kc = 0; kc < 4; ++kc) {
#pragma unroll
    for (int fc = 0; fc < 2; ++fc) {
      s16x8 bv = *(const s16x8*)(W2b + (size_t)(fc * 16 + (l & 15)) * 128 + kc * 32 + g * 8);
      acc2[fc] = __builtin_amdgcn_mfma_f32_16x16x32_bf16(e[kc], bv, acc2[fc], 0, 0, 0);
    }
  }

  float p[4] = {0.f, 0.f, 0.f, 0.f};
#pragma unroll
  for (int fc = 0; fc < 2; ++fc) {
    int col = fc * 16 + (l & 15);
    float wp = Wp[col], bb = b2[col];
#pragma unroll
    for (int reg = 0; reg < 4; ++reg)
      p[reg] += fmaxf(acc2[fc][reg] + bb, 0.f) * wp;
  }
#pragma unroll
  for (int reg = 0; reg < 4; ++reg) {
    p[reg] += __shfl_xor(p[reg], 1);
    p[reg] += __shfl_xor(p[reg], 2);
    p[reg] += __shfl_xor(p[reg], 4);
    p[reg] += __shfl_xor(p[reg], 8);
  }
  if ((l & 15) == 0) {
    float bb = bp[0];
#pragma unroll
    for (int reg = 0; reg < 4; ++reg) {
      int row = row0 + g * 4 + reg;
      if (row < L) out[row] = p[reg] + bb;
    }
  }
}

// ---------------- host launcher ----------------

extern "C" void kernel_launch(void* const* d_in, const int* in_sizes, int n_in,
                              void* d_out, int out_size, void* d_ws, size_t ws_size,
                              hipStream_t stream) {
  const float* x_virus = (const float*)d_in[0];
  const float* x_host  = (const float*)d_in[1];
  const int* src_vh = (const int*)d_in[2];
  const int* dst_vh = (const int*)d_in[3];
  const int* src_hv = (const int*)d_in[4];
  const int* dst_hv = (const int*)d_in[5];
  const int* lbl_v  = (const int*)d_in[6];
  const int* lbl_h  = (const int*)d_in[7];
  const float* Wrel[4] = {(const float*)d_in[8],  (const float*)d_in[11],
                          (const float*)d_in[14], (const float*)d_in[17]};
  const float* Wroot[4] = {(const float*)d_in[10], (const float*)d_in[13],
                           (const float*)d_in[16], (const float*)d_in[19]};
  const float* bias_c[4] = {(const float*)d_in[9], (const float*)d_in[12],
                            (const float*)d_in[15], (const float*)d_in[18]};
  const float* W1 = (const float*)d_in[20];
  const float* b1 = (const float*)d_in[21];
  const float* W2 = (const float*)d_in[22];
  const float* b2 = (const float*)d_in[23];
  const float* Wp = (const float*)d_in[24];
  const float* bp = (const float*)d_in[25];

  const int NV = in_sizes[0] / D;
  const int NH = in_sizes[1] / D;
  const int E  = in_sizes[2];
  const int L  = in_sizes[6];

  // ---- workspace carve-up ----
  char* ws = (char*)d_ws;
  size_t o = 0;
  auto balloc = [&](size_t nb) { char* p = ws + o; o += (nb + 255) & ~(size_t)255; return p; };
  unsigned short* xvb   = (unsigned short*)balloc((size_t)NV * D * 2);
  unsigned short* xhb   = (unsigned short*)balloc((size_t)NH * D * 2);
  unsigned short* xv1b  = (unsigned short*)balloc((size_t)NV * D * 2);
  unsigned short* Pvb   = (unsigned short*)balloc((size_t)NV * D * 2);
  unsigned short* xh1b  = (unsigned short*)balloc((size_t)NH * D * 2);
  unsigned short* Phb   = (unsigned short*)balloc((size_t)NH * D * 2);
  unsigned short* Wcat0 = (unsigned short*)balloc(128 * 256 * 2);
  unsigned short* Wcat1 = (unsigned short*)balloc(128 * 256 * 2);
  unsigned short* WcatFh = (unsigned short*)balloc(128 * 256 * 2);
  unsigned short* WcatFv = (unsigned short*)balloc(128 * 256 * 2);
  unsigned short* W2b = (unsigned short*)balloc(32 * 128 * 2);
  float* biasFh = (float*)balloc(128 * 4);
  float* biasFv = (float*)balloc(128 * 4);
  float* inv_h = (float*)balloc((size_t)NH * 4);
  float* inv_v = (float*)balloc((size_t)NV * 4);
  int* cnt_h = (int*)balloc((size_t)NH * 4);
  int* cnt_v = (int*)balloc((size_t)NV * 4);
  int* off_h = (int*)balloc((size_t)NH * 4);
  int* off_v = (int*)balloc((size_t)NV * 4);
  int* csr_h = (int*)balloc((size_t)E * 4);
  int* csr_v = (int*)balloc((size_t)E * 4);
  int* histmat = (int*)balloc((size_t)256 * PGB * 4);
  int* histoff = (int*)balloc((size_t)256 * PGB * 4);
  unsigned* binned = (unsigned*)balloc((size_t)E * 4);
  int* sums = (int*)balloc(256 * 4);

  auto cdiv = [](int a, int b) { return (a + b - 1) / b; };
  auto calc_shift = [](int n) { int s = 0; while ((1 << s) * 256 < n) ++s; return s; };

  // ---- CSR build, both sides (all atomics LDS-local) ----
  struct Side { const int* src; const int* dst; int N; int* csr; int* off; int* cnt; float* inv; };
  Side sides[2] = {
      {src_vh, dst_vh, NH, csr_h, off_h, cnt_h, inv_h},
      {src_hv, dst_hv, NV, csr_v, off_v, cnt_v, inv_v},
  };
  for (int s = 0; s < 2; ++s) {
    const int N = sides[s].N;
    const int shift = calc_shift(N);
    const int nbins = cdiv(N, 1 << shift);
    const int nsc = nbins * PGB;
    part_hist_k<<<PGB, 256, 0, stream>>>(sides[s].dst, histmat, E, nbins, shift);
    scan_chunk_k<<<cdiv(nsc, 1024), 256, 0, stream>>>(histmat, histoff, sums, nsc);
    scan_tops_k<<<1, 64, 0, stream>>>(sums, cdiv(nsc, 1024));
    scan_add_k<<<cdiv(nsc, 256), 256, 0, stream>>>(histoff, sums, nsc);
    part_scatter_k<<<PGB, 256, 0, stream>>>(sides[s].src, sides[s].dst, histoff, binned, E, nbins, shift);
    csr_bin_k<<<nbins, 256, 0, stream>>>(binned, histoff, sides[s].csr, sides[s].off,
                                         sides[s].cnt, sides[s].inv, E, nbins, shift, N);
  }

  // conversions + weight prep
  cvt_bf16_k<<<cdiv(NV * D / 4, 256), 256, 0, stream>>>(x_virus, xvb, NV * D / 4);
  cvt_bf16_k<<<cdiv(NH * D / 4, 256), 256, 0, stream>>>(x_host, xhb, NH * D / 4);
  pack_wcat_k<<<128, 256, 0, stream>>>(Wrel[0], Wroot[0], Wcat0);
  pack_wcat_k<<<128, 256, 0, stream>>>(Wrel[1], Wroot[1], Wcat1);
  fuse_w_k<<<128, 256, 0, stream>>>(W1, Wrel[2], Wroot[2], bias_c[2], nullptr, WcatFh, biasFh);
  fuse_w_k<<<128, 256, 0, stream>>>(W1, Wrel[3], Wroot[3], bias_c[3], b1, WcatFv, biasFv);
  cvt_bf16_k<<<cdiv(32 * 128 / 4, 256), 256, 0, stream>>>(W2, W2b, 32 * 128 / 4);

  // ---- layer 0 (relu): fused agg+conv ----
  agg_conv_k<<<cdiv(NH, 128), 256, 0, stream>>>(xvb, xhb, csr_h, off_h, cnt_h, inv_h,
                                                Wcat0, bias_c[0], xh1b, NH, 1);
  agg_conv_k<<<cdiv(NV, 128), 256, 0, stream>>>(xhb, xvb, csr_v, off_v, cnt_v, inv_v,
                                                Wcat1, bias_c[1], xv1b, NV, 1);

  // ---- layer 1 fused with W1 (no relu): produces Pv/Ph pre-activations ----
  agg_conv_k<<<cdiv(NH, 128), 256, 0, stream>>>(xv1b, xh1b, csr_h, off_h, cnt_h, inv_h,
                                                WcatFh, biasFh, Phb, NH, 0);
  agg_conv_k<<<cdiv(NV, 128), 256, 0, stream>>>(xh1b, xv1b, csr_v, off_v, cnt_v, inv_v,
                                                WcatFv, biasFv, Pvb, NV, 0);

  // ---- decoder ----
  dec2_k<<<cdiv(L, 64), 256, 0, stream>>>(Pvb, Phb, lbl_v, lbl_h, W2b, b2,
                                          Wp, bp, (float*)d_out, L);
}

// Round 10
// 478.146 us; speedup vs baseline: 1.8546x; 1.8546x over previous
//
#include <hip/hip_runtime.h>

// GNN: 2-layer bipartite GraphConv + link decoder.
// Round 10: R9 + fix for part_hist2_k race (per-side guarded histogram
// writes; the two sides' bin-row ranges overlap without the guard).
// Conv 64 rows/block A-preloaded, merged 2-side CSR/agg/conv dispatches.

#define D 128
#define PGB 256   // partition blocks per side

typedef float f32x4 __attribute__((ext_vector_type(4)));
typedef short s16x8 __attribute__((ext_vector_type(8)));

__device__ __forceinline__ float lo16(unsigned u) { return __uint_as_float(u << 16); }
__device__ __forceinline__ float hi16(unsigned u) { return __uint_as_float(u & 0xffff0000u); }
__device__ __forceinline__ unsigned short pkb(float f) {
  unsigned b = __float_as_uint(f);
  return (unsigned short)((b + 0x7fffu + ((b >> 16) & 1u)) >> 16);
}
__device__ __forceinline__ unsigned pk2(float a, float b) {
  return (unsigned)pkb(a) | ((unsigned)pkb(b) << 16);
}

union U4S8 { uint4 u; s16x8 s; };

// ---------------- CSR build: merged 2-side counting-sort ----------------
// Edge space concatenated: side0 = [0,E), side1 = [E,2E). Bin space
// concatenated: side0 bins [0,nbins0), side1 [nbins0, nbins0+nbins1).
// One scan over the whole histmat gives globally consistent offsets.

__global__ __launch_bounds__(256) void part_hist2_k(
    const int* __restrict__ dst0, const int* __restrict__ dst1,
    int* __restrict__ histmat, int E, int nbins0, int nbins1,
    int shift0, int shift1) {
  __shared__ int hist[256];
  const int t = threadIdx.x;
  const int side = blockIdx.x >> 8, blk = blockIdx.x & 255;
  const int* __restrict__ dst = side ? dst1 : dst0;
  const int shift = side ? shift1 : shift0;
  const int binbase = side ? nbins0 : 0;
  const int nbins = side ? nbins1 : nbins0;
  hist[t] = 0;
  __syncthreads();
  const int chunk = (E + PGB - 1) / PGB;
  const int e0 = blk * chunk, e1 = min(E, e0 + chunk);
  for (int i = e0 + t; i < e1; i += 256)
    atomicAdd(&hist[dst[i] >> shift], 1);
  __syncthreads();
  if (t < nbins)   // GUARD: each histmat row written by exactly one side
    histmat[(size_t)(binbase + t) * PGB + blk] = hist[t];
}

__global__ void scan_chunk_k(const int* __restrict__ in, int* __restrict__ out,
                             int* __restrict__ sums, int n) {
  __shared__ int lds[256];
  int t = threadIdx.x;
  int base = blockIdx.x * 1024 + t * 4;
  int v0 = (base + 0 < n) ? in[base + 0] : 0;
  int v1 = (base + 1 < n) ? in[base + 1] : 0;
  int v2 = (base + 2 < n) ? in[base + 2] : 0;
  int v3 = (base + 3 < n) ? in[base + 3] : 0;
  int s = v0 + v1 + v2 + v3;
  lds[t] = s;
  __syncthreads();
  for (int off = 1; off < 256; off <<= 1) {
    int x = (t >= off) ? lds[t - off] : 0;
    __syncthreads();
    lds[t] += x;
    __syncthreads();
  }
  int excl = lds[t] - s;
  if (t == 255) sums[blockIdx.x] = lds[255];
  if (base + 0 < n) out[base + 0] = excl; excl += v0;
  if (base + 1 < n) out[base + 1] = excl; excl += v1;
  if (base + 2 < n) out[base + 2] = excl; excl += v2;
  if (base + 3 < n) out[base + 3] = excl;
}

__global__ void scan_tops_k(int* __restrict__ sums, int nb) {
  if (threadIdx.x == 0 && blockIdx.x == 0) {
    int run = 0;
    for (int i = 0; i < nb; ++i) { int x = sums[i]; sums[i] = run; run += x; }
  }
}

__global__ void scan_add_k(int* __restrict__ out, const int* __restrict__ sums, int n) {
  int i = blockIdx.x * 256 + threadIdx.x;
  if (i < n) out[i] += sums[i >> 10];
}

__global__ __launch_bounds__(256) void part_scatter2_k(
    const int* __restrict__ src0, const int* __restrict__ dst0,
    const int* __restrict__ src1, const int* __restrict__ dst1,
    const int* __restrict__ histoff, unsigned* __restrict__ binned,
    int E, int nbins0, int nbins1, int shift0, int shift1) {
  __shared__ int cur[256];
  const int t = threadIdx.x;
  const int side = blockIdx.x >> 8, blk = blockIdx.x & 255;
  const int* __restrict__ src = side ? src1 : src0;
  const int* __restrict__ dst = side ? dst1 : dst0;
  const int shift = side ? shift1 : shift0;
  const int binbase = side ? nbins0 : 0;
  const int nbins = side ? nbins1 : nbins0;
  if (t < nbins) cur[t] = histoff[(size_t)(binbase + t) * PGB + blk];
  __syncthreads();
  const int chunk = (E + PGB - 1) / PGB;
  const int e0 = blk * chunk, e1 = min(E, e0 + chunk);
  const int mask = (1 << shift) - 1;
  for (int i = e0 + t; i < e1; i += 256) {
    int d = dst[i], s = src[i];
    int b = d >> shift;
    int p = atomicAdd(&cur[b], 1);   // LDS atomic
    binned[p] = ((unsigned)(d & mask) << 17) | (unsigned)s;
  }
}

__global__ __launch_bounds__(256) void csr_bin2_k(
    const unsigned* __restrict__ binned, const int* __restrict__ histoff,
    int* __restrict__ csr0, int* __restrict__ off0, int* __restrict__ cnt0, float* __restrict__ inv0,
    int* __restrict__ csr1, int* __restrict__ off1, int* __restrict__ cnt1, float* __restrict__ inv1,
    int E, int nbins0, int nbinsTot, int shift0, int shift1, int N0, int N1) {
  __shared__ int lcnt[512], lex[512], tmp[256];
  const int t = threadIdx.x, bin = blockIdx.x;
  const int side = (bin >= nbins0);
  const int lb = side ? bin - nbins0 : bin;
  const int shift = side ? shift1 : shift0;
  const int N = side ? N1 : N0;
  const int ebase = side ? E : 0;
  int* __restrict__ csr = side ? csr1 : csr0;
  int* __restrict__ off = side ? off1 : off0;
  int* __restrict__ cnt = side ? cnt1 : cnt0;
  float* __restrict__ inv = side ? inv1 : inv0;
  const int bw = 1 << shift;
  const int e0 = histoff[(size_t)bin * PGB];
  const int e1 = (bin + 1 < nbinsTot) ? histoff[(size_t)(bin + 1) * PGB] : 2 * E;
  lcnt[t] = 0; lcnt[t + 256] = 0;
  __syncthreads();
  for (int i = e0 + t; i < e1; i += 256)
    atomicAdd(&lcnt[binned[i] >> 17], 1);   // LDS atomic
  __syncthreads();
  int a = lcnt[t], b = lcnt[t + 256];
  tmp[t] = a; __syncthreads();
  for (int o = 1; o < 256; o <<= 1) {
    int x = (t >= o) ? tmp[t - o] : 0;
    __syncthreads(); tmp[t] += x; __syncthreads();
  }
  int inclA = tmp[t], totA = tmp[255];
  __syncthreads();
  tmp[t] = b; __syncthreads();
  for (int o = 1; o < 256; o <<= 1) {
    int x = (t >= o) ? tmp[t - o] : 0;
    __syncthreads(); tmp[t] += x; __syncthreads();
  }
  int inclB = tmp[t];
  lex[t] = inclA - a;
  lex[t + 256] = totA + inclB - b;
  __syncthreads();
  const int based = lb << shift;
  const int nd = min(bw, N - based);
  for (int dl = t; dl < nd; dl += 256) {
    int c = lcnt[dl];
    off[based + dl] = e0 - ebase + lex[dl];
    cnt[based + dl] = c;
    inv[based + dl] = 1.0f / fmaxf((float)c, 1.0f);
  }
  __syncthreads();
  lcnt[t] = lex[t]; lcnt[t + 256] = lex[t + 256];
  __syncthreads();
  for (int i = e0 + t; i < e1; i += 256) {
    unsigned u = binned[i];
    int dl = (int)(u >> 17);
    int p = atomicAdd(&lcnt[dl], 1);   // LDS atomic
    csr[e0 - ebase + p] = (int)(u & 0x1FFFFu);
  }
}

// ---------------- conversions / weight prep ----------------

__global__ void cvt_bf16_k(const float* __restrict__ in, unsigned short* __restrict__ out, int n4) {
  int i = blockIdx.x * 256 + threadIdx.x;
  if (i < n4) {
    float4 v = ((const float4*)in)[i];
    ushort4 o;
    o.x = pkb(v.x); o.y = pkb(v.y); o.z = pkb(v.z); o.w = pkb(v.w);
    ((ushort4*)out)[i] = o;
  }
}

__global__ void pack_wcat_k(const float* __restrict__ Wrel, const float* __restrict__ Wroot,
                            unsigned short* __restrict__ Wcat) {
  int idx = blockIdx.x * 256 + threadIdx.x;  // 32768
  int n = idx >> 8, k = idx & 255;
  float v = (k < 128) ? Wrel[(n << 7) + k] : Wroot[(n << 7) + k - 128];
  Wcat[idx] = pkb(v);
}

// WcatF[i][kk] = sum_o W1[i][o] * (kk<128 ? Wrel[o][kk] : Wroot[o][kk-128]);
// biasF[i] = sum_o W1[i][o]*brel[o] (+ b1[i] if b1 != null)
__global__ __launch_bounds__(256) void fuse_w_k(
    const float* __restrict__ W1, const float* __restrict__ Wrel,
    const float* __restrict__ Wroot, const float* __restrict__ brel,
    const float* __restrict__ b1, unsigned short* __restrict__ Wf,
    float* __restrict__ biasF) {
  const int i = blockIdx.x;      // output channel 0..127
  const int kk = threadIdx.x;    // 0..255
  const float* __restrict__ Wsrc = (kk < 128) ? Wrel : Wroot;
  const int k = kk & 127;
  float s = 0.f;
  for (int o = 0; o < 128; ++o)
    s += W1[i * 128 + o] * Wsrc[o * 128 + k];
  Wf[i * 256 + kk] = pkb(s);
  if (kk == 0) {
    float sb = b1 ? b1[i] : 0.f;
    for (int o = 0; o < 128; ++o) sb += W1[i * 128 + o] * brel[o];
    biasF[i] = sb;
  }
}

// ---------------- merged aggregation (both sides), one wave/dst ----------------

__global__ __launch_bounds__(256) void agg2_k(
    const unsigned short* __restrict__ xs0, const int* __restrict__ csr0,
    const int* __restrict__ off0, const int* __restrict__ cnt0,
    const float* __restrict__ inv0, unsigned short* __restrict__ mean0, int n0,
    const unsigned short* __restrict__ xs1, const int* __restrict__ csr1,
    const int* __restrict__ off1, const int* __restrict__ cnt1,
    const float* __restrict__ inv1, unsigned short* __restrict__ mean1, int n1,
    int nblk0) {
  int blk = blockIdx.x;
  const unsigned short* __restrict__ xsrc;
  const int* __restrict__ csr; const int* __restrict__ offp;
  const int* __restrict__ cntp; const float* __restrict__ invp;
  unsigned short* __restrict__ mean; int ndst;
  if (blk < nblk0) {
    xsrc = xs0; csr = csr0; offp = off0; cntp = cnt0; invp = inv0; mean = mean0; ndst = n0;
  } else {
    blk -= nblk0;
    xsrc = xs1; csr = csr1; offp = off1; cntp = cnt1; invp = inv1; mean = mean1; ndst = n1;
  }
  int wid = blk * 4 + (threadIdx.x >> 6);
  int lane = threadIdx.x & 63;
  if (wid >= ndst) return;
  int o = offp[wid], deg = cntp[wid];
  int q = lane >> 4, sl = lane & 15;
  float acc[8] = {0.f, 0.f, 0.f, 0.f, 0.f, 0.f, 0.f, 0.f};
  int sN[4];
#pragma unroll
  for (int j = 0; j < 4; ++j) {
    int e = j * 4 + q;
    sN[j] = (e < deg) ? csr[o + e] : -1;
  }
  for (int i = 0; i < deg; i += 16) {
    int cu[4];
#pragma unroll
    for (int j = 0; j < 4; ++j) {
      cu[j] = sN[j];
      int e = i + 16 + j * 4 + q;
      sN[j] = (e < deg) ? csr[o + e] : -1;
    }
    uint4 v[4];
#pragma unroll
    for (int j = 0; j < 4; ++j)
      if (cu[j] >= 0) v[j] = *(const uint4*)(xsrc + (size_t)cu[j] * 128 + sl * 8);
#pragma unroll
    for (int j = 0; j < 4; ++j) {
      if (cu[j] >= 0) {
        acc[0] += lo16(v[j].x); acc[1] += hi16(v[j].x);
        acc[2] += lo16(v[j].y); acc[3] += hi16(v[j].y);
        acc[4] += lo16(v[j].z); acc[5] += hi16(v[j].z);
        acc[6] += lo16(v[j].w); acc[7] += hi16(v[j].w);
      }
    }
  }
#pragma unroll
  for (int j = 0; j < 8; ++j) {
    acc[j] += __shfl_xor(acc[j], 16);
    acc[j] += __shfl_xor(acc[j], 32);
  }
  if (q == 0) {
    float iv = invp[wid];
    uint4 r;
    r.x = pk2(acc[0] * iv, acc[1] * iv);
    r.y = pk2(acc[2] * iv, acc[3] * iv);
    r.z = pk2(acc[4] * iv, acc[5] * iv);
    r.w = pk2(acc[6] * iv, acc[7] * iv);
    *(uint4*)(mean + (size_t)wid * 128 + sl * 8) = r;
  }
}

// ---------------- merged conv GEMM (both sides), 64 rows/block ----------------
// Wave w owns rows blk*64 + w*16 .. +16. All 8 A-frags preloaded; inner loop
// is pure B-load (L2) + MFMA. out = [A1|A2] @ W^T + bias.

__global__ __launch_bounds__(256) void conv2_k(
    const unsigned short* __restrict__ A1a, const unsigned short* __restrict__ A2a,
    const unsigned short* __restrict__ Wa, const float* __restrict__ ba,
    unsigned short* __restrict__ outa, int na,
    const unsigned short* __restrict__ A1b, const unsigned short* __restrict__ A2b,
    const unsigned short* __restrict__ Wb, const float* __restrict__ bb_,
    unsigned short* __restrict__ outb, int nb, int nblk0, int relu) {
  int blk = blockIdx.x;
  const unsigned short *A1, *A2, *W;
  const float* bias; unsigned short* out; int n;
  if (blk < nblk0) { A1 = A1a; A2 = A2a; W = Wa; bias = ba; out = outa; n = na; }
  else { blk -= nblk0; A1 = A1b; A2 = A2b; W = Wb; bias = bb_; out = outb; n = nb; }

  const int t = threadIdx.x;
  const int l = t & 63, wv = t >> 6;
  const int g = l >> 4;
  const int row0 = blk * 64 + wv * 16;
  int r = row0 + (l & 15); r = r < n ? r : n - 1;

  s16x8 av[8];
#pragma unroll
  for (int c = 0; c < 4; ++c)
    av[c] = *(const s16x8*)(A1 + (size_t)r * 128 + c * 32 + g * 8);
#pragma unroll
  for (int c = 0; c < 4; ++c)
    av[4 + c] = *(const s16x8*)(A2 + (size_t)r * 128 + c * 32 + g * 8);

  f32x4 acc[8] = {};
#pragma unroll
  for (int ch = 0; ch < 8; ++ch) {
#pragma unroll
    for (int fc = 0; fc < 8; ++fc) {
      s16x8 bv = *(const s16x8*)(W + (size_t)(fc * 16 + (l & 15)) * 256 + ch * 32 + g * 8);
      acc[fc] = __builtin_amdgcn_mfma_f32_16x16x32_bf16(av[ch], bv, acc[fc], 0, 0, 0);
    }
  }

#pragma unroll
  for (int fc = 0; fc < 8; ++fc) {
    int col = fc * 16 + (l & 15);
    float bv = bias[col];
    int rbase = row0 + g * 4;
#pragma unroll
    for (int reg = 0; reg < 4; ++reg) {
      int row = rbase + reg;
      if (row < n) {
        float v = acc[fc][reg] + bv;
        if (relu) v = fmaxf(v, 0.f);
        out[(size_t)row * 128 + col] = pkb(v);
      }
    }
  }
}

// ---------------- decoder: h1 = relu(Pv[lv]-Ph[lh]); stage2 MFMA; dot ----------

__global__ __launch_bounds__(256) void dec2_k(
    const unsigned short* __restrict__ Pv, const unsigned short* __restrict__ Ph,
    const int* __restrict__ lv, const int* __restrict__ lh,
    const unsigned short* __restrict__ W2b, const float* __restrict__ b2,
    const float* __restrict__ Wp, const float* __restrict__ bp,
    float* __restrict__ out, int L) {
  const int t = threadIdx.x;
  const int l = t & 63, wv = t >> 6;
  const int g = l >> 4;
  const int row0 = blockIdx.x * 64 + wv * 16;

  int rowc = row0 + (l & 15);
  rowc = rowc < L ? rowc : L - 1;
  const int iv = lv[rowc], ih = lh[rowc];
  const unsigned short* __restrict__ pv = Pv + (size_t)iv * 128 + g * 8;
  const unsigned short* __restrict__ ph = Ph + (size_t)ih * 128 + g * 8;

  uint4 A[4], B[4];
#pragma unroll
  for (int ch = 0; ch < 4; ++ch) A[ch] = *(const uint4*)(pv + ch * 32);
#pragma unroll
  for (int ch = 0; ch < 4; ++ch) B[ch] = *(const uint4*)(ph + ch * 32);

  s16x8 e[4];
#pragma unroll
  for (int ch = 0; ch < 4; ++ch) {
    U4S8 u;
    u.u.x = pk2(fmaxf(lo16(A[ch].x) - lo16(B[ch].x), 0.f), fmaxf(hi16(A[ch].x) - hi16(B[ch].x), 0.f));
    u.u.y = pk2(fmaxf(lo16(A[ch].y) - lo16(B[ch].y), 0.f), fmaxf(hi16(A[ch].y) - hi16(B[ch].y), 0.f));
    u.u.z = pk2(fmaxf(lo16(A[ch].z) - lo16(B[ch].z), 0.f), fmaxf(hi16(A[ch].z) - hi16(B[ch].z), 0.f));
    u.u.w = pk2(fmaxf(lo16(A[ch].w) - lo16(B[ch].w), 0.f), fmaxf(hi16(A[ch].w) - hi16(B[ch].w), 0.f));
    e[ch] = u.s;
  }

  f32x4 acc2[2] = {};
#pragma unroll
  for (int kc = 0; kc < 4; ++kc) {
#pragma unroll
    for (int fc = 0; fc < 2; ++fc) {
      s16x8 bv = *(const s16x8*)(W2b + (size_t)(fc * 16 + (l & 15)) * 128 + kc * 32 + g * 8);
      acc2[fc] = __builtin_amdgcn_mfma_f32_16x16x32_bf16(e[kc], bv, acc2[fc], 0, 0, 0);
    }
  }

  float p[4] = {0.f, 0.f, 0.f, 0.f};
#pragma unroll
  for (int fc = 0; fc < 2; ++fc) {
    int col = fc * 16 + (l & 15);
    float wp = Wp[col], bb = b2[col];
#pragma unroll
    for (int reg = 0; reg < 4; ++reg)
      p[reg] += fmaxf(acc2[fc][reg] + bb, 0.f) * wp;
  }
#pragma unroll
  for (int reg = 0; reg < 4; ++reg) {
    p[reg] += __shfl_xor(p[reg], 1);
    p[reg] += __shfl_xor(p[reg], 2);
    p[reg] += __shfl_xor(p[reg], 4);
    p[reg] += __shfl_xor(p[reg], 8);
  }
  if ((l & 15) == 0) {
    float bb = bp[0];
#pragma unroll
    for (int reg = 0; reg < 4; ++reg) {
      int row = row0 + g * 4 + reg;
      if (row < L) out[row] = p[reg] + bb;
    }
  }
}

// ---------------- host launcher ----------------

extern "C" void kernel_launch(void* const* d_in, const int* in_sizes, int n_in,
                              void* d_out, int out_size, void* d_ws, size_t ws_size,
                              hipStream_t stream) {
  const float* x_virus = (const float*)d_in[0];
  const float* x_host  = (const float*)d_in[1];
  const int* src_vh = (const int*)d_in[2];
  const int* dst_vh = (const int*)d_in[3];
  const int* src_hv = (const int*)d_in[4];
  const int* dst_hv = (const int*)d_in[5];
  const int* lbl_v  = (const int*)d_in[6];
  const int* lbl_h  = (const int*)d_in[7];
  const float* Wrel[4] = {(const float*)d_in[8],  (const float*)d_in[11],
                          (const float*)d_in[14], (const float*)d_in[17]};
  const float* Wroot[4] = {(const float*)d_in[10], (const float*)d_in[13],
                           (const float*)d_in[16], (const float*)d_in[19]};
  const float* bias_c[4] = {(const float*)d_in[9], (const float*)d_in[12],
                            (const float*)d_in[15], (const float*)d_in[18]};
  const float* W1 = (const float*)d_in[20];
  const float* b1 = (const float*)d_in[21];
  const float* W2 = (const float*)d_in[22];
  const float* b2 = (const float*)d_in[23];
  const float* Wp = (const float*)d_in[24];
  const float* bp = (const float*)d_in[25];

  const int NV = in_sizes[0] / D;
  const int NH = in_sizes[1] / D;
  const int E  = in_sizes[2];
  const int L  = in_sizes[6];

  // ---- workspace carve-up ----
  char* ws = (char*)d_ws;
  size_t o = 0;
  auto balloc = [&](size_t nb) { char* p = ws + o; o += (nb + 255) & ~(size_t)255; return p; };
  unsigned short* xvb   = (unsigned short*)balloc((size_t)NV * D * 2);
  unsigned short* xhb   = (unsigned short*)balloc((size_t)NH * D * 2);
  unsigned short* xv1b  = (unsigned short*)balloc((size_t)NV * D * 2);
  unsigned short* Pvb   = (unsigned short*)balloc((size_t)NV * D * 2);
  unsigned short* xh1b  = (unsigned short*)balloc((size_t)NH * D * 2);
  unsigned short* Phb   = (unsigned short*)balloc((size_t)NH * D * 2);
  unsigned short* mean_v = (unsigned short*)balloc((size_t)NV * D * 2);
  unsigned short* mean_h = (unsigned short*)balloc((size_t)NH * D * 2);
  unsigned short* Wcat0 = (unsigned short*)balloc(128 * 256 * 2);
  unsigned short* Wcat1 = (unsigned short*)balloc(128 * 256 * 2);
  unsigned short* WcatFh = (unsigned short*)balloc(128 * 256 * 2);
  unsigned short* WcatFv = (unsigned short*)balloc(128 * 256 * 2);
  unsigned short* W2b = (unsigned short*)balloc(32 * 128 * 2);
  float* biasFh = (float*)balloc(128 * 4);
  float* biasFv = (float*)balloc(128 * 4);
  float* inv_h = (float*)balloc((size_t)NH * 4);
  float* inv_v = (float*)balloc((size_t)NV * 4);
  int* cnt_h = (int*)balloc((size_t)NH * 4);
  int* cnt_v = (int*)balloc((size_t)NV * 4);
  int* off_h = (int*)balloc((size_t)NH * 4);
  int* off_v = (int*)balloc((size_t)NV * 4);
  int* csr_h = (int*)balloc((size_t)E * 4);
  int* csr_v = (int*)balloc((size_t)E * 4);
  int* histmat = (int*)balloc((size_t)512 * PGB * 4);
  int* histoff = (int*)balloc((size_t)512 * PGB * 4);
  unsigned* binned = (unsigned*)balloc((size_t)2 * E * 4);
  int* sums = (int*)balloc(512 * 4);

  auto cdiv = [](int a, int b) { return (a + b - 1) / b; };
  auto calc_shift = [](int n) { int s = 0; while ((1 << s) * 256 < n) ++s; return s; };

  // ---- merged CSR build (all atomics LDS-local) ----
  const int shift0 = calc_shift(NH), shift1 = calc_shift(NV);
  const int nbins0 = cdiv(NH, 1 << shift0), nbins1 = cdiv(NV, 1 << shift1);
  const int nbinsTot = nbins0 + nbins1;
  const int nsc = nbinsTot * PGB;
  part_hist2_k<<<512, 256, 0, stream>>>(dst_vh, dst_hv, histmat, E,
                                        nbins0, nbins1, shift0, shift1);
  scan_chunk_k<<<cdiv(nsc, 1024), 256, 0, stream>>>(histmat, histoff, sums, nsc);
  scan_tops_k<<<1, 64, 0, stream>>>(sums, cdiv(nsc, 1024));
  scan_add_k<<<cdiv(nsc, 256), 256, 0, stream>>>(histoff, sums, nsc);
  part_scatter2_k<<<512, 256, 0, stream>>>(src_vh, dst_vh, src_hv, dst_hv,
                                           histoff, binned, E, nbins0, nbins1,
                                           shift0, shift1);
  csr_bin2_k<<<nbinsTot, 256, 0, stream>>>(binned, histoff,
                                           csr_h, off_h, cnt_h, inv_h,
                                           csr_v, off_v, cnt_v, inv_v,
                                           E, nbins0, nbinsTot, shift0, shift1, NH, NV);

  // conversions + weight prep
  cvt_bf16_k<<<cdiv(NV * D / 4, 256), 256, 0, stream>>>(x_virus, xvb, NV * D / 4);
  cvt_bf16_k<<<cdiv(NH * D / 4, 256), 256, 0, stream>>>(x_host, xhb, NH * D / 4);
  pack_wcat_k<<<128, 256, 0, stream>>>(Wrel[0], Wroot[0], Wcat0);
  pack_wcat_k<<<128, 256, 0, stream>>>(Wrel[1], Wroot[1], Wcat1);
  fuse_w_k<<<128, 256, 0, stream>>>(W1, Wrel[2], Wroot[2], bias_c[2], nullptr, WcatFh, biasFh);
  fuse_w_k<<<128, 256, 0, stream>>>(W1, Wrel[3], Wroot[3], bias_c[3], b1, WcatFv, biasFv);
  cvt_bf16_k<<<cdiv(32 * 128 / 4, 256), 256, 0, stream>>>(W2, W2b, 32 * 128 / 4);

  const int nbh4 = cdiv(NH, 4), nbv4 = cdiv(NV, 4);
  const int nbh64 = cdiv(NH, 64), nbv64 = cdiv(NV, 64);

  // ---- layer 0 (relu): merged agg then merged conv ----
  agg2_k<<<nbh4 + nbv4, 256, 0, stream>>>(
      xvb, csr_h, off_h, cnt_h, inv_h, mean_h, NH,
      xhb, csr_v, off_v, cnt_v, inv_v, mean_v, NV, nbh4);
  conv2_k<<<nbh64 + nbv64, 256, 0, stream>>>(
      mean_h, xhb, Wcat0, bias_c[0], xh1b, NH,
      mean_v, xvb, Wcat1, bias_c[1], xv1b, NV, nbh64, 1);

  // ---- layer 1 fused with W1 (no relu): produces Ph/Pv pre-activations ----
  agg2_k<<<nbh4 + nbv4, 256, 0, stream>>>(
      xv1b, csr_h, off_h, cnt_h, inv_h, mean_h, NH,
      xh1b, csr_v, off_v, cnt_v, inv_v, mean_v, NV, nbh4);
  conv2_k<<<nbh64 + nbv64, 256, 0, stream>>>(
      mean_h, xh1b, WcatFh, biasFh, Phb, NH,
      mean_v, xv1b, WcatFv, biasFv, Pvb, NV, nbh64, 0);

  // ---- decoder ----
  dec2_k<<<cdiv(L, 64), 256, 0, stream>>>(Pvb, Phb, lbl_v, lbl_h, W2b, b2,
                                          Wp, bp, (float*)d_out, L);
}